// Round 1
// baseline (683.207 us; speedup 1.0000x reference)
//
#include <hip/hip_runtime.h>
#include <hip/hip_bf16.h>

#define NQH 64
#define NKVH 8
#define DH 64
#define SEQ 1024
#define HID 2880
#define QKV_N 5120   // (NQ+2*NKV)*DH
#define ATTN_N 4096  // NQ*DH
#define WIN 128

typedef __attribute__((ext_vector_type(8))) __bf16 bf16x8;
typedef __attribute__((ext_vector_type(4))) float f32x4;

__device__ __forceinline__ ushort f2bf(float x) {
    union { float f; unsigned int u; } c; c.f = x;
    unsigned int u = c.u;
    unsigned int r = (u + 0x7FFFu + ((u >> 16) & 1u)) >> 16;
    return (ushort)r;
}

// ---------------------------------------------------------------- convert
__global__ __launch_bounds__(256) void convert_f32_bf16(
    const float* __restrict__ in, ushort* __restrict__ out, int n4)
{
    int idx = blockIdx.x * blockDim.x + threadIdx.x;
    int stride = gridDim.x * blockDim.x;
    for (int i = idx; i < n4; i += stride) {
        float4 v = reinterpret_cast<const float4*>(in)[i];
        ushort4 o;
        o.x = f2bf(v.x); o.y = f2bf(v.y); o.z = f2bf(v.z); o.w = f2bf(v.w);
        reinterpret_cast<ushort4*>(out)[i] = o;
    }
}

// ---------------------------------------------------------------- GEMM (bf16 MFMA, 64x64 tile)
// A: [M][K] (f32 or bf16), B: [K][N] bf16, C: [M][N] f32, C = A@B + bias
template<bool A_IS_F32>
__global__ __launch_bounds__(256) void gemm_bias_kernel(
    const void* __restrict__ Aptr, const ushort* __restrict__ B,
    const float* __restrict__ bias, float* __restrict__ C,
    int M, int N, int K)
{
    __shared__ ushort Alds[64][40];   // [row][k], padded
    __shared__ ushort Blds[64][40];   // [col][k], padded
    const int n0 = blockIdx.x * 64;
    const int m0 = blockIdx.y * 64;
    const int tid = threadIdx.x;
    const int w = tid >> 6;
    const int lane = tid & 63;

    f32x4 acc[4];
#pragma unroll
    for (int i = 0; i < 4; i++) acc[i] = (f32x4){0.f, 0.f, 0.f, 0.f};

    const int ar = tid >> 2;          // 0..63 (A tile row)
    const int ac = (tid & 3) * 8;     // 0,8,16,24 (A tile k)
    const int bkr = tid >> 3;         // 0..31 (B tile k)
    const int bc = (tid & 7) * 8;     // 0..56 (B tile col)

    for (int k0 = 0; k0 < K; k0 += 32) {
        // stage A 64x32 -> bf16 LDS
        {
            union { ushort t[8]; uint4 v; } u;
            if (A_IS_F32) {
                const float* Af = (const float*)Aptr + (size_t)(m0 + ar) * K + k0 + ac;
                float4 v0 = *(const float4*)Af;
                float4 v1 = *(const float4*)(Af + 4);
                u.t[0] = f2bf(v0.x); u.t[1] = f2bf(v0.y); u.t[2] = f2bf(v0.z); u.t[3] = f2bf(v0.w);
                u.t[4] = f2bf(v1.x); u.t[5] = f2bf(v1.y); u.t[6] = f2bf(v1.z); u.t[7] = f2bf(v1.w);
            } else {
                const ushort* Ab = (const ushort*)Aptr + (size_t)(m0 + ar) * K + k0 + ac;
                u.v = *(const uint4*)Ab;
            }
            *reinterpret_cast<uint4*>(&Alds[ar][ac]) = u.v;
        }
        // stage B 32x64 -> transposed bf16 LDS [col][k]
        {
            union { ushort t[8]; uint4 v; } u;
            const ushort* Bp = B + (size_t)(k0 + bkr) * N + n0 + bc;
            u.v = *(const uint4*)Bp;
#pragma unroll
            for (int j = 0; j < 8; j++) Blds[bc + j][bkr] = u.t[j];
        }
        __syncthreads();
        const int row = (w << 4) + (lane & 15);
        const int koff = (lane >> 4) * 8;
        bf16x8 af = *reinterpret_cast<const bf16x8*>(&Alds[row][koff]);
#pragma unroll
        for (int cb = 0; cb < 4; cb++) {
            bf16x8 bfr = *reinterpret_cast<const bf16x8*>(&Blds[cb * 16 + (lane & 15)][koff]);
            acc[cb] = __builtin_amdgcn_mfma_f32_16x16x32_bf16(af, bfr, acc[cb], 0, 0, 0);
        }
        __syncthreads();
    }
    // epilogue: D row=(lane>>4)*4+r, col=lane&15  [verified layout]
    const int lc = lane & 15;
    const int rbase = m0 + (w << 4) + (lane >> 4) * 4;
#pragma unroll
    for (int cb = 0; cb < 4; cb++) {
        int gc = n0 + cb * 16 + lc;
        float bv = bias[gc];
#pragma unroll
        for (int r = 0; r < 4; r++) {
            C[(size_t)(rbase + r) * N + gc] = acc[cb][r] + bv;
        }
    }
}

// ---------------------------------------------------------------- RoPE (in place on qkv, q + k heads)
__global__ __launch_bounds__(256) void rope_kernel(
    float* __restrict__ qkv, const float* __restrict__ cosp, const float* __restrict__ sinp)
{
    int idx = blockIdx.x * blockDim.x + threadIdx.x;   // SEQ*72*32 threads
    int d = idx & 31;
    int t = idx >> 5;
    int h = t % 72;
    int i = t / 72;
    int col = (h < 64) ? (h * 64 + d) : (4096 + (h - 64) * 64 + d);
    float c = cosp[i * 32 + d];
    float s = sinp[i * 32 + d];
    float* p = qkv + (size_t)i * QKV_N + col;
    float x1 = p[0];
    float x2 = p[32];
    p[0] = x1 * c - x2 * s;
    p[32] = x2 * c + x1 * s;
}

// ---------------------------------------------------------------- attention (f32, one wave per (head, query))
__global__ __launch_bounds__(256) void attn_kernel(
    const float* __restrict__ qkv, const float* __restrict__ sinks,
    ushort* __restrict__ attn_out)
{
    __shared__ float q_lds[4][64];
    __shared__ float p_lds[4][128];
    const int w = threadIdx.x >> 6;
    const int lane = threadIdx.x & 63;
    const int wid = blockIdx.x * 4 + w;      // 0..65535
    const int hq = wid >> 10;                // 0..63
    const int i = wid & 1023;                // query position
    const int hk = hq >> 3;                  // G=8

    q_lds[w][lane] = qkv[(size_t)i * QKV_N + hq * 64 + lane];
    __syncthreads();

    const int kstart = (i > WIN - 1) ? (i - (WIN - 1)) : 0;
    const int klen = i - kstart + 1;         // 1..128

    const float* kbase = qkv + 4096 + (size_t)hk * 64;
    const float* k0p = kbase + (size_t)(kstart + lane) * QKV_N;
    const float* k1p = kbase + (size_t)(kstart + lane + 64) * QKV_N;

    float s0 = 0.f, s1 = 0.f;
#pragma unroll
    for (int d = 0; d < 64; d += 4) {
        float4 q4 = *(const float4*)&q_lds[w][d];
        float4 ka = *(const float4*)&k0p[d];
        float4 kb = *(const float4*)&k1p[d];
        s0 += q4.x * ka.x + q4.y * ka.y + q4.z * ka.z + q4.w * ka.w;
        s1 += q4.x * kb.x + q4.y * kb.y + q4.z * kb.z + q4.w * kb.w;
    }
    s0 *= 0.125f;
    s1 *= 0.125f;
    if (lane >= klen) s0 = -1e30f;
    if (lane + 64 >= klen) s1 = -1e30f;

    float snk = sinks[hq];
    float m = fmaxf(s0, s1);
#pragma unroll
    for (int off = 1; off < 64; off <<= 1) m = fmaxf(m, __shfl_xor(m, off));
    m = fmaxf(m, snk);

    float p0 = __expf(s0 - m);
    float p1 = __expf(s1 - m);
    float sum = p0 + p1;
#pragma unroll
    for (int off = 1; off < 64; off <<= 1) sum += __shfl_xor(sum, off);
    sum += __expf(snk - m);
    float inv = 1.f / sum;

    p_lds[w][lane] = p0;
    p_lds[w][64 + lane] = p1;
    __syncthreads();

    const float* vbase = qkv + 4608 + (size_t)hk * 64 + lane;
    float out = 0.f;
#pragma unroll 2
    for (int j = 0; j < klen; ++j) {
        out += p_lds[w][j] * vbase[(size_t)(kstart + j) * QKV_N];
    }
    attn_out[(size_t)i * ATTN_N + hq * 64 + lane] = f2bf(out * inv);
}

// ---------------------------------------------------------------- launch
extern "C" void kernel_launch(void* const* d_in, const int* in_sizes, int n_in,
                              void* d_out, int out_size, void* d_ws, size_t ws_size,
                              hipStream_t stream)
{
    const float* hidden = (const float*)d_in[0];
    const float* cosp   = (const float*)d_in[1];
    const float* sinp   = (const float*)d_in[2];
    const float* w_qkv  = (const float*)d_in[3];
    const float* b_qkv  = (const float*)d_in[4];
    const float* w_o    = (const float*)d_in[5];
    const float* b_o    = (const float*)d_in[6];
    const float* sinks  = (const float*)d_in[7];
    // d_in[8]=k_cache, d_in[9]=v_cache (zero), d_in[10]=kv_len (==0): unused.

    char* ws = (char*)d_ws;
    size_t off = 0;
    ushort* wqkv_b = (ushort*)(ws + off); off += (size_t)HID * QKV_N * 2;
    ushort* wo_b   = (ushort*)(ws + off); off += (size_t)ATTN_N * HID * 2;
    float*  qkv    = (float*)(ws + off);  off += (size_t)SEQ * QKV_N * 4;
    ushort* attn_b = (ushort*)(ws + off); off += (size_t)SEQ * ATTN_N * 2;
    if (off > ws_size) return;  // fail visibly rather than corrupt

    convert_f32_bf16<<<2048, 256, 0, stream>>>(w_qkv, wqkv_b, HID * QKV_N / 4);
    convert_f32_bf16<<<2048, 256, 0, stream>>>(w_o, wo_b, ATTN_N * HID / 4);

    dim3 g1(QKV_N / 64, SEQ / 64);
    gemm_bias_kernel<true><<<g1, 256, 0, stream>>>(hidden, wqkv_b, b_qkv, qkv, SEQ, QKV_N, HID);

    rope_kernel<<<SEQ * 72 * 32 / 256, 256, 0, stream>>>(qkv, cosp, sinp);

    attn_kernel<<<SEQ * NQH / 4, 256, 0, stream>>>(qkv, sinks, attn_b);

    dim3 g2(HID / 64, SEQ / 64);
    gemm_bias_kernel<false><<<g2, 256, 0, stream>>>(attn_b, wo_b, b_o, (float*)d_out, SEQ, HID, ATTN_N);
}

// Round 2
// 505.147 us; speedup vs baseline: 1.3525x; 1.3525x over previous
//
#include <hip/hip_runtime.h>
#include <hip/hip_bf16.h>

#define NQH 64
#define NKVH 8
#define DH 64
#define SEQ 1024
#define HID 2880
#define QKV_N 5120   // (NQ+2*NKV)*DH
#define ATTN_N 4096  // NQ*DH
#define WIN 128
#define WO_NPAD 2944 // 23*128

typedef __attribute__((ext_vector_type(8))) __bf16 bf16x8;
typedef __attribute__((ext_vector_type(4))) float f32x4;

#define GLOAD_LDS16(g, l) \
    __builtin_amdgcn_global_load_lds((const __attribute__((address_space(1))) void*)(g), \
                                     (__attribute__((address_space(3))) void*)(l), 16, 0, 0)

__device__ __forceinline__ ushort f2bf(float x) {
    union { float f; unsigned int u; } c; c.f = x;
    unsigned int u = c.u;
    unsigned int r = (u + 0x7FFFu + ((u >> 16) & 1u)) >> 16;
    return (ushort)r;
}

// ---------------------------------------------------------------- convert (plain)
__global__ __launch_bounds__(256) void convert_f32_bf16(
    const float* __restrict__ in, ushort* __restrict__ out, int n4)
{
    int idx = blockIdx.x * blockDim.x + threadIdx.x;
    int stride = gridDim.x * blockDim.x;
    for (int i = idx; i < n4; i += stride) {
        float4 v = reinterpret_cast<const float4*>(in)[i];
        ushort4 o;
        o.x = f2bf(v.x); o.y = f2bf(v.y); o.z = f2bf(v.z); o.w = f2bf(v.w);
        reinterpret_cast<ushort4*>(out)[i] = o;
    }
}

// ---------------------------------------------------------------- transpose+convert
// in: [K][N] f32  ->  out: [Npad][K] bf16 (rows >= N zero-filled). K,Npad multiples of 64.
__global__ __launch_bounds__(256) void transpose_convert(
    const float* __restrict__ in, ushort* __restrict__ out, int K, int N)
{
    __shared__ ushort tile[64][80];   // row stride 160B (16B-aligned for uint4)
    const int bk = blockIdx.x * 64;   // k tile origin
    const int bn = blockIdx.y * 64;   // n tile origin
    const int tid = threadIdx.x;
    const bool inb = bn < N;          // whole tile valid or whole tile pad (N % 64 == 0)

#pragma unroll
    for (int it = 0; it < 4; ++it) {
        int r = it * 16 + (tid >> 4);         // k offset 0..63
        int c4 = (tid & 15) * 4;              // n offset
        float4 v = make_float4(0.f, 0.f, 0.f, 0.f);
        if (inb) v = *(const float4*)&in[(size_t)(bk + r) * N + bn + c4];
        tile[c4 + 0][r] = f2bf(v.x);
        tile[c4 + 1][r] = f2bf(v.y);
        tile[c4 + 2][r] = f2bf(v.z);
        tile[c4 + 3][r] = f2bf(v.w);
    }
    __syncthreads();
#pragma unroll
    for (int it = 0; it < 2; ++it) {
        int nr = it * 32 + (tid >> 3);        // n offset 0..63
        int c8 = (tid & 7) * 8;               // k offset
        uint4 v = *(const uint4*)&tile[nr][c8];
        *(uint4*)&out[(size_t)(bn + nr) * K + bk + c8] = v;
    }
}

// ---------------------------------------------------------------- GEMM 128x128 (m97 structure)
// A: [M][K] bf16, BT: [Npad][K] bf16, C: [M][Nreal] f32 = A@B + bias. K % 32 == 0.
__global__ __launch_bounds__(256) void gemm128(
    const ushort* __restrict__ A, const ushort* __restrict__ BT,
    const float* __restrict__ bias, float* __restrict__ C,
    int K, int Nreal)
{
    __shared__ ushort Al[128 * 32];
    __shared__ ushort Bl[128 * 32];
    const int t = threadIdx.x;
    const int lane = t & 63;
    const int w = t >> 6;
    const int m0 = blockIdx.y * 128;
    const int n0 = blockIdx.x * 128;

    // staging: chunk c = t (rows 0..63) and c = t+256 (rows 64..127); 16B per chunk
    const int r1 = t >> 2, kc = t & 3;
    const int r2 = 64 + r1;
    const ushort* a1 = A + (size_t)(m0 + r1) * K + ((kc ^ (r1 & 3)) * 8);
    const ushort* a2 = A + (size_t)(m0 + r2) * K + ((kc ^ (r2 & 3)) * 8);
    const ushort* b1 = BT + (size_t)(n0 + r1) * K + ((kc ^ (r1 & 3)) * 8);
    const ushort* b2 = BT + (size_t)(n0 + r2) * K + ((kc ^ (r2 & 3)) * 8);
    ushort* al1 = &Al[t * 8];  ushort* al2 = &Al[2048 + t * 8];
    ushort* bl1 = &Bl[t * 8];  ushort* bl2 = &Bl[2048 + t * 8];

    // fragment read offsets (element units), swizzled to match source pre-swizzle
    const int wr = w >> 1, wc = w & 1;
    int aoff[4], boff[4];
#pragma unroll
    for (int i = 0; i < 4; ++i) {
        int row = wr * 64 + i * 16 + (lane & 15);
        aoff[i] = row * 32 + (((lane >> 4) ^ (row & 3)) * 8);
        int col = wc * 64 + i * 16 + (lane & 15);
        boff[i] = col * 32 + (((lane >> 4) ^ (col & 3)) * 8);
    }

    f32x4 acc[4][4];
#pragma unroll
    for (int i = 0; i < 4; ++i)
#pragma unroll
        for (int j = 0; j < 4; ++j) acc[i][j] = (f32x4){0.f, 0.f, 0.f, 0.f};

    for (int k0 = 0; k0 < K; k0 += 32) {
        GLOAD_LDS16(a1, al1);
        GLOAD_LDS16(a2, al2);
        GLOAD_LDS16(b1, bl1);
        GLOAD_LDS16(b2, bl2);
        a1 += 32; a2 += 32; b1 += 32; b2 += 32;
        __syncthreads();
        bf16x8 af[4], bfr[4];
#pragma unroll
        for (int i = 0; i < 4; ++i) af[i] = *(const bf16x8*)&Al[aoff[i]];
#pragma unroll
        for (int i = 0; i < 4; ++i) bfr[i] = *(const bf16x8*)&Bl[boff[i]];
#pragma unroll
        for (int mi = 0; mi < 4; ++mi)
#pragma unroll
            for (int ni = 0; ni < 4; ++ni)
                acc[mi][ni] = __builtin_amdgcn_mfma_f32_16x16x32_bf16(af[mi], bfr[ni], acc[mi][ni], 0, 0, 0);
        __syncthreads();
    }

    // epilogue: C row=(lane>>4)*4+r (+16*mi +64*wr), col=lane&15 (+16*ni +64*wc)
    const int csub = (lane >> 4) * 4;
#pragma unroll
    for (int ni = 0; ni < 4; ++ni) {
        int col = n0 + wc * 64 + ni * 16 + (lane & 15);
        if (col < Nreal) {
            float bv = bias[col];
#pragma unroll
            for (int mi = 0; mi < 4; ++mi) {
                int row = m0 + wr * 64 + mi * 16 + csub;
#pragma unroll
                for (int r = 0; r < 4; ++r)
                    C[(size_t)(row + r) * Nreal + col] = acc[mi][ni][r] + bv;
            }
        }
    }
}

// ---------------------------------------------------------------- RoPE (in place on qkv)
__global__ __launch_bounds__(256) void rope_kernel(
    float* __restrict__ qkv, const float* __restrict__ cosp, const float* __restrict__ sinp)
{
    int idx = blockIdx.x * blockDim.x + threadIdx.x;   // SEQ*72*32 threads
    int d = idx & 31;
    int t = idx >> 5;
    int h = t % 72;
    int i = t / 72;
    int col = (h < 64) ? (h * 64 + d) : (4096 + (h - 64) * 64 + d);
    float c = cosp[i * 32 + d];
    float s = sinp[i * 32 + d];
    float* p = qkv + (size_t)i * QKV_N + col;
    float x1 = p[0];
    float x2 = p[32];
    p[0] = x1 * c - x2 * s;
    p[32] = x2 * c + x1 * s;
}

// ---------------------------------------------------------------- attention (f32, one wave per (head, query))
__global__ __launch_bounds__(256) void attn_kernel(
    const float* __restrict__ qkv, const float* __restrict__ sinks,
    ushort* __restrict__ attn_out)
{
    __shared__ float q_lds[4][64];
    __shared__ float p_lds[4][128];
    const int w = threadIdx.x >> 6;
    const int lane = threadIdx.x & 63;
    const int wid = blockIdx.x * 4 + w;      // 0..65535
    const int hq = wid >> 10;                // 0..63
    const int i = wid & 1023;                // query position
    const int hk = hq >> 3;                  // G=8

    q_lds[w][lane] = qkv[(size_t)i * QKV_N + hq * 64 + lane];
    __syncthreads();

    const int kstart = (i > WIN - 1) ? (i - (WIN - 1)) : 0;
    const int klen = i - kstart + 1;         // 1..128

    const float* kbase = qkv + 4096 + (size_t)hk * 64;
    const float* k0p = kbase + (size_t)(kstart + lane) * QKV_N;
    const float* k1p = kbase + (size_t)(kstart + lane + 64) * QKV_N;

    float s0 = 0.f, s1 = 0.f;
#pragma unroll
    for (int d = 0; d < 64; d += 4) {
        float4 q4 = *(const float4*)&q_lds[w][d];
        float4 ka = *(const float4*)&k0p[d];
        float4 kb = *(const float4*)&k1p[d];
        s0 += q4.x * ka.x + q4.y * ka.y + q4.z * ka.z + q4.w * ka.w;
        s1 += q4.x * kb.x + q4.y * kb.y + q4.z * kb.z + q4.w * kb.w;
    }
    s0 *= 0.125f;
    s1 *= 0.125f;
    if (lane >= klen) s0 = -1e30f;
    if (lane + 64 >= klen) s1 = -1e30f;

    float snk = sinks[hq];
    float m = fmaxf(s0, s1);
#pragma unroll
    for (int off = 1; off < 64; off <<= 1) m = fmaxf(m, __shfl_xor(m, off));
    m = fmaxf(m, snk);

    float p0 = __expf(s0 - m);
    float p1 = __expf(s1 - m);
    float sum = p0 + p1;
#pragma unroll
    for (int off = 1; off < 64; off <<= 1) sum += __shfl_xor(sum, off);
    sum += __expf(snk - m);
    float inv = 1.f / sum;

    p_lds[w][lane] = p0;        // zero for masked keys (exp(-1e30-m)==0)
    p_lds[w][64 + lane] = p1;
    __syncthreads();

    // PV: fixed 128 iterations, 16 loads in flight per batch
    const float* vbase = qkv + 4608 + (size_t)hk * 64 + lane;
    float out = 0.f;
#pragma unroll 2
    for (int jb = 0; jb < 128; jb += 16) {
        float v[16];
#pragma unroll
        for (int u = 0; u < 16; ++u)
            v[u] = vbase[(size_t)(kstart + jb + u) * QKV_N];
        float4 pa = *(const float4*)&p_lds[w][jb + 0];
        float4 pb = *(const float4*)&p_lds[w][jb + 4];
        float4 pc = *(const float4*)&p_lds[w][jb + 8];
        float4 pd = *(const float4*)&p_lds[w][jb + 12];
        out += pa.x * v[0] + pa.y * v[1] + pa.z * v[2] + pa.w * v[3];
        out += pb.x * v[4] + pb.y * v[5] + pb.z * v[6] + pb.w * v[7];
        out += pc.x * v[8] + pc.y * v[9] + pc.z * v[10] + pc.w * v[11];
        out += pd.x * v[12] + pd.y * v[13] + pd.z * v[14] + pd.w * v[15];
    }
    attn_out[(size_t)i * ATTN_N + hq * 64 + lane] = f2bf(out * inv);
}

// ---------------------------------------------------------------- launch
extern "C" void kernel_launch(void* const* d_in, const int* in_sizes, int n_in,
                              void* d_out, int out_size, void* d_ws, size_t ws_size,
                              hipStream_t stream)
{
    const float* hidden = (const float*)d_in[0];
    const float* cosp   = (const float*)d_in[1];
    const float* sinp   = (const float*)d_in[2];
    const float* w_qkv  = (const float*)d_in[3];
    const float* b_qkv  = (const float*)d_in[4];
    const float* w_o    = (const float*)d_in[5];
    const float* b_o    = (const float*)d_in[6];
    const float* sinks  = (const float*)d_in[7];
    // d_in[8]=k_cache, d_in[9]=v_cache (zero), d_in[10]=kv_len (==0): unused.

    char* ws = (char*)d_ws;
    size_t off = 0;
    ushort* wqkvT = (ushort*)(ws + off); off += (size_t)QKV_N * HID * 2;      // [5120][2880]
    ushort* woT   = (ushort*)(ws + off); off += (size_t)WO_NPAD * ATTN_N * 2; // [2944][4096]
    float*  qkv   = (float*)(ws + off);  off += (size_t)SEQ * QKV_N * 4;
    // union region: hidden_b (gemm1 A) then attn_b (gemm2 A) — lifetimes disjoint
    ushort* hidden_b = (ushort*)(ws + off);
    ushort* attn_b   = (ushort*)(ws + off); off += (size_t)SEQ * ATTN_N * 2;
    if (off > ws_size) return;  // fail visibly rather than corrupt

    // weight transposes + hidden convert
    transpose_convert<<<dim3(HID / 64, QKV_N / 64), 256, 0, stream>>>(w_qkv, wqkvT, HID, QKV_N);
    transpose_convert<<<dim3(ATTN_N / 64, WO_NPAD / 64), 256, 0, stream>>>(w_o, woT, ATTN_N, HID);
    convert_f32_bf16<<<2048, 256, 0, stream>>>(hidden, hidden_b, SEQ * HID / 4);

    // QKV projection
    gemm128<<<dim3(QKV_N / 128, SEQ / 128), 256, 0, stream>>>(hidden_b, wqkvT, b_qkv, qkv, HID, QKV_N);

    rope_kernel<<<SEQ * 72 * 32 / 256, 256, 0, stream>>>(qkv, cosp, sinp);

    attn_kernel<<<SEQ * NQH / 4, 256, 0, stream>>>(qkv, sinks, attn_b);

    // output projection
    gemm128<<<dim3(WO_NPAD / 128, SEQ / 128), 256, 0, stream>>>(attn_b, woT, b_o, (float*)d_out, ATTN_N, HID);
}

// Round 3
// 214.514 us; speedup vs baseline: 3.1849x; 2.3548x over previous
//
#include <hip/hip_runtime.h>
#include <hip/hip_bf16.h>

#define NQH 64
#define NKVH 8
#define DH 64
#define SEQ 1024
#define HID 2880
#define QKV_N 5120   // (NQ+2*NKV)*DH
#define ATTN_N 4096  // NQ*DH
#define WIN 128
#define WO_NPAD 2944 // 23*128
#define SCALE_F 0.125f

typedef __attribute__((ext_vector_type(8))) __bf16 bf16x8;
typedef __attribute__((ext_vector_type(4))) float f32x4;

#define GLOAD_LDS16(g, l) \
    __builtin_amdgcn_global_load_lds((const __attribute__((address_space(1))) void*)(g), \
                                     (__attribute__((address_space(3))) void*)(l), 16, 0, 0)

__device__ __forceinline__ ushort f2bf(float x) {
    union { float f; unsigned int u; } c; c.f = x;
    unsigned int u = c.u;
    unsigned int r = (u + 0x7FFFu + ((u >> 16) & 1u)) >> 16;
    return (ushort)r;
}

// ---------------------------------------------------------------- convert (plain)
__global__ __launch_bounds__(256) void convert_f32_bf16(
    const float* __restrict__ in, ushort* __restrict__ out, int n4)
{
    int idx = blockIdx.x * blockDim.x + threadIdx.x;
    int stride = gridDim.x * blockDim.x;
    for (int i = idx; i < n4; i += stride) {
        float4 v = reinterpret_cast<const float4*>(in)[i];
        ushort4 o;
        o.x = f2bf(v.x); o.y = f2bf(v.y); o.z = f2bf(v.z); o.w = f2bf(v.w);
        reinterpret_cast<ushort4*>(out)[i] = o;
    }
}

// ---------------------------------------------------------------- transpose+convert
// in: [K][N] f32  ->  out: [Npad][K] bf16 (rows >= N zero-filled). K,Npad multiples of 64.
__global__ __launch_bounds__(256) void transpose_convert(
    const float* __restrict__ in, ushort* __restrict__ out, int K, int N)
{
    __shared__ ushort tile[64][80];   // row stride 160B (16B-aligned for uint4)
    const int bk = blockIdx.x * 64;   // k tile origin
    const int bn = blockIdx.y * 64;   // n tile origin
    const int tid = threadIdx.x;
    const bool inb = bn < N;          // whole tile valid or whole tile pad (N % 64 == 0)

#pragma unroll
    for (int it = 0; it < 4; ++it) {
        int r = it * 16 + (tid >> 4);         // k offset 0..63
        int c4 = (tid & 15) * 4;              // n offset
        float4 v = make_float4(0.f, 0.f, 0.f, 0.f);
        if (inb) v = *(const float4*)&in[(size_t)(bk + r) * N + bn + c4];
        tile[c4 + 0][r] = f2bf(v.x);
        tile[c4 + 1][r] = f2bf(v.y);
        tile[c4 + 2][r] = f2bf(v.z);
        tile[c4 + 3][r] = f2bf(v.w);
    }
    __syncthreads();
#pragma unroll
    for (int it = 0; it < 2; ++it) {
        int nr = it * 32 + (tid >> 3);        // n offset 0..63
        int c8 = (tid & 7) * 8;               // k offset
        uint4 v = *(const uint4*)&tile[nr][c8];
        *(uint4*)&out[(size_t)(bn + nr) * K + bk + c8] = v;
    }
}

// ---------------------------------------------------------------- GEMM 128x128 (m97 structure)
// A: [M][K] bf16, BT: [Npad][K] bf16, C: [M][Nreal] f32 = A@B + bias. K % 32 == 0.
__global__ __launch_bounds__(256) void gemm128(
    const ushort* __restrict__ A, const ushort* __restrict__ BT,
    const float* __restrict__ bias, float* __restrict__ C,
    int K, int Nreal)
{
    __shared__ ushort Al[128 * 32];
    __shared__ ushort Bl[128 * 32];
    const int t = threadIdx.x;
    const int lane = t & 63;
    const int w = t >> 6;
    const int m0 = blockIdx.y * 128;
    const int n0 = blockIdx.x * 128;

    // staging: chunk c = t (rows 0..63) and c = t+256 (rows 64..127); 16B per chunk
    const int r1 = t >> 2, kc = t & 3;
    const int r2 = 64 + r1;
    const ushort* a1 = A + (size_t)(m0 + r1) * K + ((kc ^ (r1 & 3)) * 8);
    const ushort* a2 = A + (size_t)(m0 + r2) * K + ((kc ^ (r2 & 3)) * 8);
    const ushort* b1 = BT + (size_t)(n0 + r1) * K + ((kc ^ (r1 & 3)) * 8);
    const ushort* b2 = BT + (size_t)(n0 + r2) * K + ((kc ^ (r2 & 3)) * 8);
    ushort* al1 = &Al[t * 8];  ushort* al2 = &Al[2048 + t * 8];
    ushort* bl1 = &Bl[t * 8];  ushort* bl2 = &Bl[2048 + t * 8];

    // fragment read offsets (element units), swizzled to match source pre-swizzle
    const int wr = w >> 1, wc = w & 1;
    int aoff[4], boff[4];
#pragma unroll
    for (int i = 0; i < 4; ++i) {
        int row = wr * 64 + i * 16 + (lane & 15);
        aoff[i] = row * 32 + (((lane >> 4) ^ (row & 3)) * 8);
        int col = wc * 64 + i * 16 + (lane & 15);
        boff[i] = col * 32 + (((lane >> 4) ^ (col & 3)) * 8);
    }

    f32x4 acc[4][4];
#pragma unroll
    for (int i = 0; i < 4; ++i)
#pragma unroll
        for (int j = 0; j < 4; ++j) acc[i][j] = (f32x4){0.f, 0.f, 0.f, 0.f};

    for (int k0 = 0; k0 < K; k0 += 32) {
        GLOAD_LDS16(a1, al1);
        GLOAD_LDS16(a2, al2);
        GLOAD_LDS16(b1, bl1);
        GLOAD_LDS16(b2, bl2);
        a1 += 32; a2 += 32; b1 += 32; b2 += 32;
        __syncthreads();
        bf16x8 af[4], bfr[4];
#pragma unroll
        for (int i = 0; i < 4; ++i) af[i] = *(const bf16x8*)&Al[aoff[i]];
#pragma unroll
        for (int i = 0; i < 4; ++i) bfr[i] = *(const bf16x8*)&Bl[boff[i]];
#pragma unroll
        for (int mi = 0; mi < 4; ++mi)
#pragma unroll
            for (int ni = 0; ni < 4; ++ni)
                acc[mi][ni] = __builtin_amdgcn_mfma_f32_16x16x32_bf16(af[mi], bfr[ni], acc[mi][ni], 0, 0, 0);
        __syncthreads();
    }

    // epilogue: C row=(lane>>4)*4+r (+16*mi +64*wr), col=lane&15 (+16*ni +64*wc)
    const int csub = (lane >> 4) * 4;
#pragma unroll
    for (int ni = 0; ni < 4; ++ni) {
        int col = n0 + wc * 64 + ni * 16 + (lane & 15);
        if (col < Nreal) {
            float bv = bias[col];
#pragma unroll
            for (int mi = 0; mi < 4; ++mi) {
                int row = m0 + wr * 64 + mi * 16 + csub;
#pragma unroll
                for (int r = 0; r < 4; ++r)
                    C[(size_t)(row + r) * Nreal + col] = acc[mi][ni][r] + bv;
            }
        }
    }
}

// ---------------------------------------------------------------- RoPE (in place on qkv)
__global__ __launch_bounds__(256) void rope_kernel(
    float* __restrict__ qkv, const float* __restrict__ cosp, const float* __restrict__ sinp)
{
    int idx = blockIdx.x * blockDim.x + threadIdx.x;   // SEQ*72*32 threads
    int d = idx & 31;
    int t = idx >> 5;
    int h = t % 72;
    int i = t / 72;
    int col = (h < 64) ? (h * 64 + d) : (4096 + (h - 64) * 64 + d);
    float c = cosp[i * 32 + d];
    float s = sinp[i * 32 + d];
    float* p = qkv + (size_t)i * QKV_N + col;
    float x1 = p[0];
    float x2 = p[32];
    p[0] = x1 * c - x2 * s;
    p[32] = x2 * c + x1 * s;
}

// ---------------------------------------------------------------- MFMA flash attention
// Block = (q-tile of 32, kv-head). 512 threads (8 waves), each wave owns 32 score rows
// (rows R = 32w..32w+31; R = g*32+q_local over the 8 q-heads of this kv head group? No:
//  R in 0..255 maps g = R>>5, q_local = R&31). Keys: 160 staged, kbase = q0-128.
// Swapped QK^T: S_T[key][row] = mfma(A=K, B=Q). Lane holds full score row -> lane-local
// softmax (+shfl_xor 16/32 across the 4 lane-groups). P scaled by 1/denom lane-local,
// bounced through per-wave LDS chunk into A-fragment layout for PV.
__global__ __launch_bounds__(512) void attn_mfma_kernel(
    const float* __restrict__ qkv, const float* __restrict__ sinks,
    ushort* __restrict__ attn_out)
{
    __shared__ __align__(16) ushort Kl[160][72];    // [key][d], pad 64->72 (2-way free)
    __shared__ __align__(16) ushort Vt[64][168];    // [d][key], pad 160->168 (2-way free)
    __shared__ __align__(16) ushort Pl[8][32][40];  // per-wave P chunk [row][32 keys], pad->40
    const int t = threadIdx.x;
    const int w = t >> 6;
    const int l = t & 63;
    const int g4 = l >> 4;
    const int r15 = l & 15;
    const int q0 = blockIdx.x * 32;
    const int hk = blockIdx.y;
    const int kbase = q0 - 128;

    // ---- stage K [160][64] f32->bf16 and V^T [64][160]
#pragma unroll
    for (int i = 0; i < 5; ++i) {
        int idx = i * 512 + t;             // 0..2559
        int row = idx >> 4;                // 0..159
        int c4 = (idx & 15) * 4;           // 0..60
        int j = kbase + row;
        float4 kv = make_float4(0.f, 0.f, 0.f, 0.f);
        float4 vv = make_float4(0.f, 0.f, 0.f, 0.f);
        if (j >= 0) {
            kv = *(const float4*)&qkv[(size_t)j * QKV_N + 4096 + hk * 64 + c4];
            vv = *(const float4*)&qkv[(size_t)j * QKV_N + 4608 + hk * 64 + c4];
        }
        ushort4 kp;
        kp.x = f2bf(kv.x); kp.y = f2bf(kv.y); kp.z = f2bf(kv.z); kp.w = f2bf(kv.w);
        *(ushort4*)&Kl[row][c4] = kp;
        Vt[c4 + 0][row] = f2bf(vv.x);
        Vt[c4 + 1][row] = f2bf(vv.y);
        Vt[c4 + 2][row] = f2bf(vv.z);
        Vt[c4 + 3][row] = f2bf(vv.w);
    }

    // ---- Q fragments (B operand: lane supplies col = score-row = r15+16ct, k = d)
    bf16x8 qf[2][2];
#pragma unroll
    for (int ct = 0; ct < 2; ++ct) {
        int R = w * 32 + ct * 16 + r15;
        int q = q0 + (R & 31);
        int hq = hk * 8 + (R >> 5);
        const float* qb = &qkv[(size_t)q * QKV_N + hq * 64];
#pragma unroll
        for (int s = 0; s < 2; ++s) {
            float4 a = *(const float4*)&qb[s * 32 + g4 * 8];
            float4 b = *(const float4*)&qb[s * 32 + g4 * 8 + 4];
            union { ushort u[8]; bf16x8 v; } pk;
            pk.u[0] = f2bf(a.x * SCALE_F); pk.u[1] = f2bf(a.y * SCALE_F);
            pk.u[2] = f2bf(a.z * SCALE_F); pk.u[3] = f2bf(a.w * SCALE_F);
            pk.u[4] = f2bf(b.x * SCALE_F); pk.u[5] = f2bf(b.y * SCALE_F);
            pk.u[6] = f2bf(b.z * SCALE_F); pk.u[7] = f2bf(b.w * SCALE_F);
            qf[ct][s] = pk.v;
        }
    }
    __syncthreads();

    // ---- S^T = K @ Q^T : D row = key = 16kt+4g4+r, col = score-row = 16ct+r15 (+32w)
    f32x4 sc[10][2];
#pragma unroll
    for (int kt = 0; kt < 10; ++kt) {
        sc[kt][0] = (f32x4){0.f, 0.f, 0.f, 0.f};
        sc[kt][1] = (f32x4){0.f, 0.f, 0.f, 0.f};
    }
#pragma unroll
    for (int kt = 0; kt < 10; ++kt) {
#pragma unroll
        for (int s = 0; s < 2; ++s) {
            bf16x8 kf = *(const bf16x8*)&Kl[kt * 16 + r15][s * 32 + g4 * 8];
            sc[kt][0] = __builtin_amdgcn_mfma_f32_16x16x32_bf16(kf, qf[0][s], sc[kt][0], 0, 0, 0);
            sc[kt][1] = __builtin_amdgcn_mfma_f32_16x16x32_bf16(kf, qf[1][s], sc[kt][1], 0, 0, 0);
        }
    }

    // ---- masked softmax, per score-row; fold sink and 1/denom (all lane-local)
    const int minkey = 128 - q0;          // key_local >= minkey  <=>  j >= 0
#pragma unroll
    for (int ct = 0; ct < 2; ++ct) {
        int R = w * 32 + ct * 16 + r15;
        int ql = R & 31;
        float snk = sinks[hk * 8 + (R >> 5)];
#pragma unroll
        for (int kt = 0; kt < 10; ++kt)
#pragma unroll
            for (int r = 0; r < 4; ++r) {
                int key = kt * 16 + g4 * 4 + r;
                // allowed: q_local < key <= q_local+128 (window+causal), key >= minkey (j>=0)
                bool ok = (key > ql) && (key <= ql + 128) && (key >= minkey);
                if (!ok) sc[kt][ct][r] = -1e30f;
            }
        float m = snk;
#pragma unroll
        for (int kt = 0; kt < 10; ++kt)
#pragma unroll
            for (int r = 0; r < 4; ++r) m = fmaxf(m, sc[kt][ct][r]);
        m = fmaxf(m, __shfl_xor(m, 16));
        m = fmaxf(m, __shfl_xor(m, 32));
        float sum = 0.f;
#pragma unroll
        for (int kt = 0; kt < 10; ++kt)
#pragma unroll
            for (int r = 0; r < 4; ++r) {
                float p = __expf(sc[kt][ct][r] - m);
                sc[kt][ct][r] = p;
                sum += p;
            }
        sum += __shfl_xor(sum, 16);
        sum += __shfl_xor(sum, 32);
        sum += __expf(snk - m);
        float iv = 1.0f / sum;
#pragma unroll
        for (int kt = 0; kt < 10; ++kt)
#pragma unroll
            for (int r = 0; r < 4; ++r) sc[kt][ct][r] *= iv;
    }

    // ---- PV: out[row][d] = sum_key P[row][key] * V[key][d]
    // P bounced through per-wave LDS chunk (32 keys at a time) into A-frag layout.
    f32x4 pv[2][4];
#pragma unroll
    for (int mi = 0; mi < 2; ++mi)
#pragma unroll
        for (int ni = 0; ni < 4; ++ni) pv[mi][ni] = (f32x4){0.f, 0.f, 0.f, 0.f};

#pragma unroll
    for (int s = 0; s < 5; ++s) {
        // write: lane holds P[row=16ct+r15][key 16kt+4g4+r] -> keys 4g4..4g4+3 consecutive
#pragma unroll
        for (int ct = 0; ct < 2; ++ct)
#pragma unroll
            for (int kh = 0; kh < 2; ++kh) {
                int kt = 2 * s + kh;
                ushort4 p4;
                p4.x = f2bf(sc[kt][ct][0]);
                p4.y = f2bf(sc[kt][ct][1]);
                p4.z = f2bf(sc[kt][ct][2]);
                p4.w = f2bf(sc[kt][ct][3]);
                *(ushort4*)&Pl[w][ct * 16 + r15][kh * 16 + g4 * 4] = p4;
            }
        // read A-frags (row = r15+16mi, k = keys g4*8..+8) + V B-frags, 16 MFMA
        // (same-wave ds_write->ds_read: DS ops are in-order per wave; compiler adds lgkmcnt)
#pragma unroll
        for (int mi = 0; mi < 2; ++mi) {
            bf16x8 pf = *(const bf16x8*)&Pl[w][mi * 16 + r15][g4 * 8];
#pragma unroll
            for (int ni = 0; ni < 4; ++ni) {
                bf16x8 vf = *(const bf16x8*)&Vt[ni * 16 + r15][s * 32 + g4 * 8];
                pv[mi][ni] = __builtin_amdgcn_mfma_f32_16x16x32_bf16(pf, vf, pv[mi][ni], 0, 0, 0);
            }
        }
    }

    // ---- write attn output (bf16): D row = 16mi+4g4+r (+32w), col = d = 16ni+r15
#pragma unroll
    for (int mi = 0; mi < 2; ++mi)
#pragma unroll
        for (int r = 0; r < 4; ++r) {
            int R = w * 32 + mi * 16 + g4 * 4 + r;
            int q = q0 + (R & 31);
            int hq = hk * 8 + (R >> 5);
            ushort* ob = &attn_out[(size_t)q * ATTN_N + hq * 64 + r15];
#pragma unroll
            for (int ni = 0; ni < 4; ++ni)
                ob[ni * 16] = f2bf(pv[mi][ni][r]);
        }
}

// ---------------------------------------------------------------- launch
extern "C" void kernel_launch(void* const* d_in, const int* in_sizes, int n_in,
                              void* d_out, int out_size, void* d_ws, size_t ws_size,
                              hipStream_t stream)
{
    const float* hidden = (const float*)d_in[0];
    const float* cosp   = (const float*)d_in[1];
    const float* sinp   = (const float*)d_in[2];
    const float* w_qkv  = (const float*)d_in[3];
    const float* b_qkv  = (const float*)d_in[4];
    const float* w_o    = (const float*)d_in[5];
    const float* b_o    = (const float*)d_in[6];
    const float* sinks  = (const float*)d_in[7];
    // d_in[8]=k_cache, d_in[9]=v_cache (zero), d_in[10]=kv_len (==0): unused.

    char* ws = (char*)d_ws;
    size_t off = 0;
    ushort* wqkvT = (ushort*)(ws + off); off += (size_t)QKV_N * HID * 2;      // [5120][2880]
    ushort* woT   = (ushort*)(ws + off); off += (size_t)WO_NPAD * ATTN_N * 2; // [2944][4096]
    float*  qkv   = (float*)(ws + off);  off += (size_t)SEQ * QKV_N * 4;
    // union region: hidden_b (gemm1 A) then attn_b (gemm2 A) — lifetimes disjoint
    ushort* hidden_b = (ushort*)(ws + off);
    ushort* attn_b   = (ushort*)(ws + off); off += (size_t)SEQ * ATTN_N * 2;
    if (off > ws_size) return;  // fail visibly rather than corrupt

    // weight transposes + hidden convert
    transpose_convert<<<dim3(HID / 64, QKV_N / 64), 256, 0, stream>>>(w_qkv, wqkvT, HID, QKV_N);
    transpose_convert<<<dim3(ATTN_N / 64, WO_NPAD / 64), 256, 0, stream>>>(w_o, woT, ATTN_N, HID);
    convert_f32_bf16<<<2048, 256, 0, stream>>>(hidden, hidden_b, SEQ * HID / 4);

    // QKV projection
    gemm128<<<dim3(QKV_N / 128, SEQ / 128), 256, 0, stream>>>(hidden_b, wqkvT, b_qkv, qkv, HID, QKV_N);

    rope_kernel<<<SEQ * 72 * 32 / 256, 256, 0, stream>>>(qkv, cosp, sinp);

    // MFMA flash attention: grid (q-tiles, kv-heads)
    attn_mfma_kernel<<<dim3(SEQ / 32, NKVH), 512, 0, stream>>>(qkv, sinks, attn_b);

    // output projection
    gemm128<<<dim3(WO_NPAD / 128, SEQ / 128), 256, 0, stream>>>(attn_b, woT, b_o, (float*)d_out, ATTN_N, HID);
}

// Round 4
// 147.911 us; speedup vs baseline: 4.6190x; 1.4503x over previous
//
#include <hip/hip_runtime.h>
#include <hip/hip_bf16.h>

#define NQH 64
#define NKVH 8
#define DH 64
#define SEQ 1024
#define HID 2880
#define QKV_N 5120   // (NQ+2*NKV)*DH
#define ATTN_N 4096  // NQ*DH
#define WIN 128
#define WO_NPAD 2944 // 23*128
#define SCALE_F 0.125f

typedef __attribute__((ext_vector_type(8))) __bf16 bf16x8;
typedef __attribute__((ext_vector_type(4))) float f32x4;

#define GLOAD_LDS16(g, l) \
    __builtin_amdgcn_global_load_lds((const __attribute__((address_space(1))) void*)(g), \
                                     (__attribute__((address_space(3))) void*)(l), 16, 0, 0)

__device__ __forceinline__ ushort f2bf(float x) {
    union { float f; unsigned int u; } c; c.f = x;
    unsigned int u = c.u;
    unsigned int r = (u + 0x7FFFu + ((u >> 16) & 1u)) >> 16;
    return (ushort)r;
}

// ---------------------------------------------------------------- convert (plain)
__global__ __launch_bounds__(256) void convert_f32_bf16(
    const float* __restrict__ in, ushort* __restrict__ out, int n4)
{
    int idx = blockIdx.x * blockDim.x + threadIdx.x;
    int stride = gridDim.x * blockDim.x;
    for (int i = idx; i < n4; i += stride) {
        float4 v = reinterpret_cast<const float4*>(in)[i];
        ushort4 o;
        o.x = f2bf(v.x); o.y = f2bf(v.y); o.z = f2bf(v.z); o.w = f2bf(v.w);
        reinterpret_cast<ushort4*>(out)[i] = o;
    }
}

// ---------------------------------------------------------------- transpose+convert
// in: [K][N] f32  ->  out: [Npad][K] bf16 (rows >= N zero-filled). K,Npad multiples of 64.
__global__ __launch_bounds__(256) void transpose_convert(
    const float* __restrict__ in, ushort* __restrict__ out, int K, int N)
{
    __shared__ ushort tile[64][80];   // row stride 160B (16B-aligned for uint4)
    const int bk = blockIdx.x * 64;   // k tile origin
    const int bn = blockIdx.y * 64;   // n tile origin
    const int tid = threadIdx.x;
    const bool inb = bn < N;          // whole tile valid or whole tile pad (N % 64 == 0)

#pragma unroll
    for (int it = 0; it < 4; ++it) {
        int r = it * 16 + (tid >> 4);         // k offset 0..63
        int c4 = (tid & 15) * 4;              // n offset
        float4 v = make_float4(0.f, 0.f, 0.f, 0.f);
        if (inb) v = *(const float4*)&in[(size_t)(bk + r) * N + bn + c4];
        tile[c4 + 0][r] = f2bf(v.x);
        tile[c4 + 1][r] = f2bf(v.y);
        tile[c4 + 2][r] = f2bf(v.z);
        tile[c4 + 3][r] = f2bf(v.w);
    }
    __syncthreads();
#pragma unroll
    for (int it = 0; it < 2; ++it) {
        int nr = it * 32 + (tid >> 3);        // n offset 0..63
        int c8 = (tid & 7) * 8;               // k offset
        uint4 v = *(const uint4*)&tile[nr][c8];
        *(uint4*)&out[(size_t)(bn + nr) * K + bk + c8] = v;
    }
}

// ---------------------------------------------------------------- GEMM 64x128, BK=64
// A: [M][K] bf16, BT: [Npad][K] bf16, C: [M][ldC] f32 (+bias), K % 64 == 0.
// 256 threads = 4 waves, wave tile 32x64 (2x4 frags). Grid (N/128, M/64), M/64 == 16.
// LDS: row = 64 el = 128 B (full 32-bank span); slot swizzle = chunk ^ (row&7) -> 2-way max.
// XCD swizzle: each XCD owns contiguous bx range, walks by (B panel hot in its L2).
// ROPE: fused rotary epilogue for gemm1 (heads < 72), cols = one head per wave-half.
template<bool ROPE>
__global__ __launch_bounds__(256) void gemm64x128(
    const ushort* __restrict__ A, const ushort* __restrict__ BT,
    const float* __restrict__ bias, float* __restrict__ C,
    int K, int ldC, int Nreal,
    const float* __restrict__ cosp, const float* __restrict__ sinp)
{
    __shared__ ushort Al[64 * 64];    // 8 KB
    __shared__ ushort Bl[128 * 64];   // 16 KB
    const int t = threadIdx.x;
    const int lane = t & 63;
    const int w = t >> 6;
    const int wr = w >> 1, wc = w & 1;
    const int g4 = lane >> 4;
    const int r15 = lane & 15;

    // bijective XCD swizzle (gridDim.y == 16, nwg % 8 == 0)
    const int flat = blockIdx.x + gridDim.x * blockIdx.y;
    const int per = (gridDim.x * gridDim.y) >> 3;
    const int virt = (flat & 7) * per + (flat >> 3);
    const int m0 = (virt & 15) * 64;
    const int n0 = (virt >> 4) * 128;

    // ---- staging pointers (inverse-swizzled global source, linear LDS dest)
    const ushort* aSrc0; const ushort* aSrc1;
    ushort* aDst0; ushort* aDst1;
    {
        int lin0 = t, lin1 = 256 + t;
        int row0 = lin0 >> 3, row1 = lin1 >> 3;
        int ch0 = (lin0 & 7) ^ (row0 & 7);
        int ch1 = (lin1 & 7) ^ (row1 & 7);
        aSrc0 = A + (size_t)(m0 + row0) * K + ch0 * 8;
        aSrc1 = A + (size_t)(m0 + row1) * K + ch1 * 8;
        aDst0 = &Al[lin0 * 8];
        aDst1 = &Al[lin1 * 8];
    }
    const ushort* bSrc[4]; ushort* bDst[4];
#pragma unroll
    for (int i = 0; i < 4; ++i) {
        int lin = i * 256 + t;
        int col = lin >> 3;
        int ch = (lin & 7) ^ (col & 7);
        bSrc[i] = BT + (size_t)(n0 + col) * K + ch * 8;
        bDst[i] = &Bl[lin * 8];
    }

    // ---- fragment read offsets (element units), swizzled
    int aoff[2][2], boff[4][2];
#pragma unroll
    for (int mi = 0; mi < 2; ++mi)
#pragma unroll
        for (int ks = 0; ks < 2; ++ks) {
            int row = wr * 32 + mi * 16 + r15;
            int slot = (ks * 4 + g4) ^ (row & 7);
            aoff[mi][ks] = row * 64 + slot * 8;
        }
#pragma unroll
    for (int ni = 0; ni < 4; ++ni)
#pragma unroll
        for (int ks = 0; ks < 2; ++ks) {
            int col = wc * 64 + ni * 16 + r15;
            int slot = (ks * 4 + g4) ^ (col & 7);
            boff[ni][ks] = col * 64 + slot * 8;
        }

    f32x4 acc[2][4];
#pragma unroll
    for (int mi = 0; mi < 2; ++mi)
#pragma unroll
        for (int ni = 0; ni < 4; ++ni) acc[mi][ni] = (f32x4){0.f, 0.f, 0.f, 0.f};

    for (int k0 = 0; k0 < K; k0 += 64) {
        GLOAD_LDS16(aSrc0, aDst0);
        GLOAD_LDS16(aSrc1, aDst1);
        GLOAD_LDS16(bSrc[0], bDst[0]);
        GLOAD_LDS16(bSrc[1], bDst[1]);
        GLOAD_LDS16(bSrc[2], bDst[2]);
        GLOAD_LDS16(bSrc[3], bDst[3]);
        aSrc0 += 64; aSrc1 += 64;
        bSrc[0] += 64; bSrc[1] += 64; bSrc[2] += 64; bSrc[3] += 64;
        __syncthreads();
#pragma unroll
        for (int ks = 0; ks < 2; ++ks) {
            bf16x8 a0 = *(const bf16x8*)&Al[aoff[0][ks]];
            bf16x8 a1 = *(const bf16x8*)&Al[aoff[1][ks]];
            bf16x8 b0 = *(const bf16x8*)&Bl[boff[0][ks]];
            bf16x8 b1 = *(const bf16x8*)&Bl[boff[1][ks]];
            bf16x8 b2 = *(const bf16x8*)&Bl[boff[2][ks]];
            bf16x8 b3 = *(const bf16x8*)&Bl[boff[3][ks]];
            acc[0][0] = __builtin_amdgcn_mfma_f32_16x16x32_bf16(a0, b0, acc[0][0], 0, 0, 0);
            acc[0][1] = __builtin_amdgcn_mfma_f32_16x16x32_bf16(a0, b1, acc[0][1], 0, 0, 0);
            acc[0][2] = __builtin_amdgcn_mfma_f32_16x16x32_bf16(a0, b2, acc[0][2], 0, 0, 0);
            acc[0][3] = __builtin_amdgcn_mfma_f32_16x16x32_bf16(a0, b3, acc[0][3], 0, 0, 0);
            acc[1][0] = __builtin_amdgcn_mfma_f32_16x16x32_bf16(a1, b0, acc[1][0], 0, 0, 0);
            acc[1][1] = __builtin_amdgcn_mfma_f32_16x16x32_bf16(a1, b1, acc[1][1], 0, 0, 0);
            acc[1][2] = __builtin_amdgcn_mfma_f32_16x16x32_bf16(a1, b2, acc[1][2], 0, 0, 0);
            acc[1][3] = __builtin_amdgcn_mfma_f32_16x16x32_bf16(a1, b3, acc[1][3], 0, 0, 0);
        }
        __syncthreads();
    }

    // ---- epilogue: bias (+ optional fused RoPE), f32 store
    // D frag: row = (lane>>4)*4 + r (+16*mi +32*wr +m0), col = lane&15 (+16*ni +64*wc +n0)
    float vals[2][4][4];
#pragma unroll
    for (int ni = 0; ni < 4; ++ni) {
        int col = n0 + wc * 64 + ni * 16 + r15;
        float bv = (col < Nreal) ? bias[col] : 0.f;
#pragma unroll
        for (int mi = 0; mi < 2; ++mi)
#pragma unroll
            for (int r = 0; r < 4; ++r) vals[mi][ni][r] = acc[mi][ni][r] + bv;
    }
    if (ROPE) {
        const int head = (n0 + wc * 64) >> 6;   // wave-half = exactly one 64-col head
        if (head < 72) {                         // q heads 0..63, k heads 64..71; v passthrough
#pragma unroll
            for (int mi = 0; mi < 2; ++mi)
#pragma unroll
                for (int r = 0; r < 4; ++r) {
                    int q = m0 + wr * 32 + mi * 16 + g4 * 4 + r;
#pragma unroll
                    for (int dp = 0; dp < 2; ++dp) {
                        int d = dp * 16 + r15;
                        float c = cosp[q * 32 + d];
                        float s = sinp[q * 32 + d];
                        float x1 = vals[mi][dp][r];
                        float x2 = vals[mi][dp + 2][r];
                        vals[mi][dp][r]     = x1 * c - x2 * s;
                        vals[mi][dp + 2][r] = x2 * c + x1 * s;
                    }
                }
        }
    }
#pragma unroll
    for (int ni = 0; ni < 4; ++ni) {
        int col = n0 + wc * 64 + ni * 16 + r15;
        if (col < Nreal) {
#pragma unroll
            for (int mi = 0; mi < 2; ++mi) {
                int row = m0 + wr * 32 + mi * 16 + g4 * 4;
#pragma unroll
                for (int r = 0; r < 4; ++r)
                    C[(size_t)(row + r) * ldC + col] = vals[mi][ni][r];
            }
        }
    }
}

// ---------------------------------------------------------------- MFMA flash attention
__global__ __launch_bounds__(512) void attn_mfma_kernel(
    const float* __restrict__ qkv, const float* __restrict__ sinks,
    ushort* __restrict__ attn_out)
{
    __shared__ __align__(16) ushort Kl[160][72];    // [key][d], pad 64->72 (2-way free)
    __shared__ __align__(16) ushort Vt[64][168];    // [d][key], pad 160->168 (2-way free)
    __shared__ __align__(16) ushort Pl[8][32][40];  // per-wave P chunk [row][32 keys], pad->40
    const int t = threadIdx.x;
    const int w = t >> 6;
    const int l = t & 63;
    const int g4 = l >> 4;
    const int r15 = l & 15;
    const int q0 = blockIdx.x * 32;
    const int hk = blockIdx.y;
    const int kbase = q0 - 128;

    // ---- stage K [160][64] f32->bf16 and V^T [64][160]
#pragma unroll
    for (int i = 0; i < 5; ++i) {
        int idx = i * 512 + t;             // 0..2559
        int row = idx >> 4;                // 0..159
        int c4 = (idx & 15) * 4;           // 0..60
        int j = kbase + row;
        float4 kv = make_float4(0.f, 0.f, 0.f, 0.f);
        float4 vv = make_float4(0.f, 0.f, 0.f, 0.f);
        if (j >= 0) {
            kv = *(const float4*)&qkv[(size_t)j * QKV_N + 4096 + hk * 64 + c4];
            vv = *(const float4*)&qkv[(size_t)j * QKV_N + 4608 + hk * 64 + c4];
        }
        ushort4 kp;
        kp.x = f2bf(kv.x); kp.y = f2bf(kv.y); kp.z = f2bf(kv.z); kp.w = f2bf(kv.w);
        *(ushort4*)&Kl[row][c4] = kp;
        Vt[c4 + 0][row] = f2bf(vv.x);
        Vt[c4 + 1][row] = f2bf(vv.y);
        Vt[c4 + 2][row] = f2bf(vv.z);
        Vt[c4 + 3][row] = f2bf(vv.w);
    }

    // ---- Q fragments (B operand: lane supplies col = score-row = r15+16ct, k = d)
    bf16x8 qf[2][2];
#pragma unroll
    for (int ct = 0; ct < 2; ++ct) {
        int R = w * 32 + ct * 16 + r15;
        int q = q0 + (R & 31);
        int hq = hk * 8 + (R >> 5);
        const float* qb = &qkv[(size_t)q * QKV_N + hq * 64];
#pragma unroll
        for (int s = 0; s < 2; ++s) {
            float4 a = *(const float4*)&qb[s * 32 + g4 * 8];
            float4 b = *(const float4*)&qb[s * 32 + g4 * 8 + 4];
            union { ushort u[8]; bf16x8 v; } pk;
            pk.u[0] = f2bf(a.x * SCALE_F); pk.u[1] = f2bf(a.y * SCALE_F);
            pk.u[2] = f2bf(a.z * SCALE_F); pk.u[3] = f2bf(a.w * SCALE_F);
            pk.u[4] = f2bf(b.x * SCALE_F); pk.u[5] = f2bf(b.y * SCALE_F);
            pk.u[6] = f2bf(b.z * SCALE_F); pk.u[7] = f2bf(b.w * SCALE_F);
            qf[ct][s] = pk.v;
        }
    }
    __syncthreads();

    // ---- S^T = K @ Q^T : D row = key = 16kt+4g4+r, col = score-row = 16ct+r15 (+32w)
    f32x4 sc[10][2];
#pragma unroll
    for (int kt = 0; kt < 10; ++kt) {
        sc[kt][0] = (f32x4){0.f, 0.f, 0.f, 0.f};
        sc[kt][1] = (f32x4){0.f, 0.f, 0.f, 0.f};
    }
#pragma unroll
    for (int kt = 0; kt < 10; ++kt) {
#pragma unroll
        for (int s = 0; s < 2; ++s) {
            bf16x8 kf = *(const bf16x8*)&Kl[kt * 16 + r15][s * 32 + g4 * 8];
            sc[kt][0] = __builtin_amdgcn_mfma_f32_16x16x32_bf16(kf, qf[0][s], sc[kt][0], 0, 0, 0);
            sc[kt][1] = __builtin_amdgcn_mfma_f32_16x16x32_bf16(kf, qf[1][s], sc[kt][1], 0, 0, 0);
        }
    }

    // ---- masked softmax, per score-row; fold sink and 1/denom (all lane-local)
    const int minkey = 128 - q0;          // key_local >= minkey  <=>  j >= 0
#pragma unroll
    for (int ct = 0; ct < 2; ++ct) {
        int R = w * 32 + ct * 16 + r15;
        int ql = R & 31;
        float snk = sinks[hk * 8 + (R >> 5)];
#pragma unroll
        for (int kt = 0; kt < 10; ++kt)
#pragma unroll
            for (int r = 0; r < 4; ++r) {
                int key = kt * 16 + g4 * 4 + r;
                // allowed: q_local < key <= q_local+128 (window+causal), key >= minkey (j>=0)
                bool ok = (key > ql) && (key <= ql + 128) && (key >= minkey);
                if (!ok) sc[kt][ct][r] = -1e30f;
            }
        float m = snk;
#pragma unroll
        for (int kt = 0; kt < 10; ++kt)
#pragma unroll
            for (int r = 0; r < 4; ++r) m = fmaxf(m, sc[kt][ct][r]);
        m = fmaxf(m, __shfl_xor(m, 16));
        m = fmaxf(m, __shfl_xor(m, 32));
        float sum = 0.f;
#pragma unroll
        for (int kt = 0; kt < 10; ++kt)
#pragma unroll
            for (int r = 0; r < 4; ++r) {
                float p = __expf(sc[kt][ct][r] - m);
                sc[kt][ct][r] = p;
                sum += p;
            }
        sum += __shfl_xor(sum, 16);
        sum += __shfl_xor(sum, 32);
        sum += __expf(snk - m);
        float iv = 1.0f / sum;
#pragma unroll
        for (int kt = 0; kt < 10; ++kt)
#pragma unroll
            for (int r = 0; r < 4; ++r) sc[kt][ct][r] *= iv;
    }

    // ---- PV: out[row][d] = sum_key P[row][key] * V[key][d]
    f32x4 pv[2][4];
#pragma unroll
    for (int mi = 0; mi < 2; ++mi)
#pragma unroll
        for (int ni = 0; ni < 4; ++ni) pv[mi][ni] = (f32x4){0.f, 0.f, 0.f, 0.f};

#pragma unroll
    for (int s = 0; s < 5; ++s) {
#pragma unroll
        for (int ct = 0; ct < 2; ++ct)
#pragma unroll
            for (int kh = 0; kh < 2; ++kh) {
                int kt = 2 * s + kh;
                ushort4 p4;
                p4.x = f2bf(sc[kt][ct][0]);
                p4.y = f2bf(sc[kt][ct][1]);
                p4.z = f2bf(sc[kt][ct][2]);
                p4.w = f2bf(sc[kt][ct][3]);
                *(ushort4*)&Pl[w][ct * 16 + r15][kh * 16 + g4 * 4] = p4;
            }
#pragma unroll
        for (int mi = 0; mi < 2; ++mi) {
            bf16x8 pf = *(const bf16x8*)&Pl[w][mi * 16 + r15][g4 * 8];
#pragma unroll
            for (int ni = 0; ni < 4; ++ni) {
                bf16x8 vf = *(const bf16x8*)&Vt[ni * 16 + r15][s * 32 + g4 * 8];
                pv[mi][ni] = __builtin_amdgcn_mfma_f32_16x16x32_bf16(pf, vf, pv[mi][ni], 0, 0, 0);
            }
        }
    }

    // ---- write attn output (bf16): D row = 16mi+4g4+r (+32w), col = d = 16ni+r15
#pragma unroll
    for (int mi = 0; mi < 2; ++mi)
#pragma unroll
        for (int r = 0; r < 4; ++r) {
            int R = w * 32 + mi * 16 + g4 * 4 + r;
            int q = q0 + (R & 31);
            int hq = hk * 8 + (R >> 5);
            ushort* ob = &attn_out[(size_t)q * ATTN_N + hq * 64 + r15];
#pragma unroll
            for (int ni = 0; ni < 4; ++ni)
                ob[ni * 16] = f2bf(pv[mi][ni][r]);
        }
}

// ---------------------------------------------------------------- launch
extern "C" void kernel_launch(void* const* d_in, const int* in_sizes, int n_in,
                              void* d_out, int out_size, void* d_ws, size_t ws_size,
                              hipStream_t stream)
{
    const float* hidden = (const float*)d_in[0];
    const float* cosp   = (const float*)d_in[1];
    const float* sinp   = (const float*)d_in[2];
    const float* w_qkv  = (const float*)d_in[3];
    const float* b_qkv  = (const float*)d_in[4];
    const float* w_o    = (const float*)d_in[5];
    const float* b_o    = (const float*)d_in[6];
    const float* sinks  = (const float*)d_in[7];
    // d_in[8]=k_cache, d_in[9]=v_cache (zero), d_in[10]=kv_len (==0): unused.

    char* ws = (char*)d_ws;
    size_t off = 0;
    ushort* wqkvT = (ushort*)(ws + off); off += (size_t)QKV_N * HID * 2;      // [5120][2880]
    ushort* woT   = (ushort*)(ws + off); off += (size_t)WO_NPAD * ATTN_N * 2; // [2944][4096]
    float*  qkv   = (float*)(ws + off);  off += (size_t)SEQ * QKV_N * 4;
    // union region: hidden_b (gemm1 A) then attn_b (gemm2 A) — lifetimes disjoint
    ushort* hidden_b = (ushort*)(ws + off);
    ushort* attn_b   = (ushort*)(ws + off); off += (size_t)SEQ * ATTN_N * 2;
    if (off > ws_size) return;  // fail visibly rather than corrupt

    // weight transposes + hidden convert
    transpose_convert<<<dim3(HID / 64, QKV_N / 64), 256, 0, stream>>>(w_qkv, wqkvT, HID, QKV_N);
    transpose_convert<<<dim3(ATTN_N / 64, WO_NPAD / 64), 256, 0, stream>>>(w_o, woT, ATTN_N, HID);
    convert_f32_bf16<<<2048, 256, 0, stream>>>(hidden, hidden_b, SEQ * HID / 4);

    // QKV projection with fused RoPE epilogue
    gemm64x128<true><<<dim3(QKV_N / 128, SEQ / 64), 256, 0, stream>>>(
        hidden_b, wqkvT, b_qkv, qkv, HID, QKV_N, QKV_N, cosp, sinp);

    // MFMA flash attention: grid (q-tiles, kv-heads)
    attn_mfma_kernel<<<dim3(SEQ / 32, NKVH), 512, 0, stream>>>(qkv, sinks, attn_b);

    // output projection
    gemm64x128<false><<<dim3(WO_NPAD / 128, SEQ / 64), 256, 0, stream>>>(
        attn_b, woT, b_o, (float*)d_out, ATTN_N, HID, HID, nullptr, nullptr);
}